// Round 1
// baseline (105.791 us; speedup 1.0000x reference)
//
#include <hip/hip_runtime.h>

#define N 4096
#define LOG2E 1.4426950408889634f

__device__ __forceinline__ float fast_exp2(float x) {
#if __has_builtin(__builtin_amdgcn_exp2f)
    return __builtin_amdgcn_exp2f(x);
#else
    return exp2f(x);
#endif
}

__device__ float block_reduce_sum(float v) {
    __shared__ float red[8];
    int lane = threadIdx.x & 63;
    int wid = threadIdx.x >> 6;
    #pragma unroll
    for (int off = 32; off; off >>= 1) v += __shfl_down(v, off, 64);
    if (lane == 0) red[wid] = v;
    __syncthreads();
    if (threadIdx.x == 0) {
        int nw = (int)(blockDim.x >> 6);
        float s = red[0];
        for (int w = 1; w < nw; ++w) s += red[w];
        red[0] = s;
    }
    __syncthreads();
    float r = red[0];
    __syncthreads();   // allow safe reuse of red[] on next call
    return r;
}

// K1: per-vector stats + normalization + coefficient arrays.
// vec = b*3 + k (k=0: fused, 1: src1, 2: src2). 6 blocks x 256 threads.
__global__ void k_stats(const float* __restrict__ fused,
                        const float* __restrict__ s1,
                        const float* __restrict__ s2,
                        float* __restrict__ ws_vn,
                        float2* __restrict__ ws_ab) {
    int vec = blockIdx.x;
    int b = vec / 3, k = vec % 3;
    const float* src = (k == 0 ? fused : (k == 1 ? s1 : s2)) + b * 16384;
    int tid = threadIdx.x;
    float v[16];
    float s = 0.f;
    #pragma unroll
    for (int t = 0; t < 16; ++t) { v[t] = src[tid + t * 256]; s += v[t]; }
    float total = block_reduce_sum(s);
    float mean = total * (1.0f / 4096.0f);
    float ssq = 0.f;
    #pragma unroll
    for (int t = 0; t < 16; ++t) { float d = v[t] - mean; ssq += d * d; }
    float tssq = block_reduce_sum(ssq);
    float stdv = sqrtf(tssq / 4095.0f);            // ddof=1
    float sigma = fminf(fmaxf(0.2f * stdv, 0.001f), 1.0f);
    float inv = 1.0f / (stdv + 1e-8f);
    float c1 = -0.5f * LOG2E / (sigma * sigma);
    float* vn = ws_vn + (size_t)vec * N;
    float2* ab = ws_ab + (size_t)vec * N;
    #pragma unroll
    for (int t = 0; t < 16; ++t) {
        int i = tid + t * 256;
        float x = (v[t] - mean) * inv;
        vn[i] = x;
        ab[i] = make_float2(c1 * x * x, -2.0f * c1 * x);
    }
}

// K2: pdf (un-normalized raw sums). Tasks t=0..9: t = b*5 + p,
// p=0..2 marginal of vec p, p=3: joint(x,y1), p=4: joint(x,y2).
// grid = 10 * nib * js blocks of 256 threads; i = ib*256+tid; j-range split js ways.
__global__ void k_pdf(const float* __restrict__ ws_vn,
                      const float2* __restrict__ ws_ab,
                      float* __restrict__ part,
                      int nib, int js) {
    int bid = blockIdx.x;
    int t = bid / (nib * js);
    int rem = bid % (nib * js);
    int ib = rem / js, jsp = rem % js;
    int p = t % 5, b = t / 5;
    int i = ib * 256 + threadIdx.x;
    int jlen = N / js;
    int j0 = jsp * jlen, j1 = j0 + jlen;

    float acc0 = 0.f, acc1 = 0.f, acc2 = 0.f, acc3 = 0.f;
    if (p < 3) {
        int v = b * 3 + p;
        const float* vn = ws_vn + (size_t)v * N;
        const float2* ab = ws_ab + (size_t)v * N;
        float xi = vn[i];
        float ci = ab[i].x;
        for (int j = j0; j < j1; j += 4) {
            float2 a0 = ab[j], a1 = ab[j + 1], a2 = ab[j + 2], a3 = ab[j + 3];
            acc0 += fast_exp2(fmaf(a0.y, xi, ci) + a0.x);
            acc1 += fast_exp2(fmaf(a1.y, xi, ci) + a1.x);
            acc2 += fast_exp2(fmaf(a2.y, xi, ci) + a2.x);
            acc3 += fast_exp2(fmaf(a3.y, xi, ci) + a3.x);
        }
    } else {
        int vx = b * 3, vy = b * 3 + (p - 2);
        const float* vnx = ws_vn + (size_t)vx * N;
        const float* vny = ws_vn + (size_t)vy * N;
        const float2* abx = ws_ab + (size_t)vx * N;
        const float2* aby = ws_ab + (size_t)vy * N;
        float xi = vnx[i], yi = vny[i];
        float ci = abx[i].x + aby[i].x;
        for (int j = j0; j < j1; j += 4) {
            float2 ax0 = abx[j], ax1 = abx[j + 1], ax2 = abx[j + 2], ax3 = abx[j + 3];
            float2 ay0 = aby[j], ay1 = aby[j + 1], ay2 = aby[j + 2], ay3 = aby[j + 3];
            float e0 = fmaf(ay0.y, yi, fmaf(ax0.y, xi, ci)) + (ax0.x + ay0.x);
            float e1 = fmaf(ay1.y, yi, fmaf(ax1.y, xi, ci)) + (ax1.x + ay1.x);
            float e2 = fmaf(ay2.y, yi, fmaf(ax2.y, xi, ci)) + (ax2.x + ay2.x);
            float e3 = fmaf(ay3.y, yi, fmaf(ax3.y, xi, ci)) + (ax3.x + ay3.x);
            acc0 += fast_exp2(e0);
            acc1 += fast_exp2(e1);
            acc2 += fast_exp2(e2);
            acc3 += fast_exp2(e3);
        }
    }
    part[((size_t)t * js + jsp) * N + i] = (acc0 + acc1) + (acc2 + acc3);
}

// K3a: reduce j-split partials -> pdf (divided by N) + per-task sums. 10 blocks.
__global__ void k_reduce(const float* __restrict__ part, float* __restrict__ pdf,
                         float* __restrict__ sums, int js) {
    int t = blockIdx.x;
    float local = 0.f;
    for (int i = threadIdx.x; i < N; i += 256) {
        float s = 0.f;
        for (int q = 0; q < js; ++q) s += part[((size_t)t * js + q) * N + i];
        s *= (1.0f / N);
        pdf[(size_t)t * N + i] = s;
        local += s;
    }
    float tot = block_reduce_sum(local);
    if (threadIdx.x == 0) sums[t] = tot;
}

// K3b: MI for the 4 (b, pair) combos + final output. 1 block.
__global__ void k_mi(const float* __restrict__ pdf, const float* __restrict__ sums,
                     float* __restrict__ out) {
    float mi_total = 0.f;
    for (int c = 0; c < 4; ++c) {
        int b = c >> 1, pr = c & 1;
        int tj = b * 5 + 3 + pr;
        int tx = b * 5;
        int ty = b * 5 + 1 + pr;
        float inv_sj = 1.0f / (sums[tj] + 1e-10f);
        float inv_sx = 1.0f / (sums[tx] + 1e-10f);
        float inv_sy = 1.0f / (sums[ty] + 1e-10f);
        float local = 0.f;
        for (int i = threadIdx.x; i < N; i += 256) {
            float pj = pdf[(size_t)tj * N + i] * inv_sj;
            float px = pdf[(size_t)tx * N + i] * inv_sx;
            float py = pdf[(size_t)ty * N + i] * inv_sy;
            float ratio = (pj + 1e-10f) / (px * py + 1e-10f);
            ratio = fminf(fmaxf(ratio, 1e-10f), 1e10f);
            local += pj * __logf(ratio);
        }
        float mi = block_reduce_sum(local);
        mi_total += mi;
    }
    if (threadIdx.x == 0) out[0] = -(mi_total * 0.5f);
}

extern "C" void kernel_launch(void* const* d_in, const int* in_sizes, int n_in,
                              void* d_out, int out_size, void* d_ws, size_t ws_size,
                              hipStream_t stream) {
    const float* fused = (const float*)d_in[0];
    const float* s1    = (const float*)d_in[1];
    const float* s2    = (const float*)d_in[2];
    float* out = (float*)d_out;
    float* ws  = (float*)d_ws;

    // ws layout (in floats)
    const size_t off_vn   = 0;                       // 6*4096
    const size_t off_ab   = 6 * (size_t)N;           // 6*4096 float2 = 12*4096 floats
    const size_t off_pdf  = off_ab + 12 * (size_t)N; // 10*4096
    const size_t off_sums = off_pdf + 10 * (size_t)N;// 10 (+pad)
    const size_t off_part = off_sums + 16;           // 10*js*4096

    int js = 8;
    while (js > 1 && (off_part + (size_t)10 * js * N) * 4 > ws_size) js >>= 1;

    float*  ws_vn   = ws + off_vn;
    float2* ws_ab   = (float2*)(ws + off_ab);
    float*  ws_pdf  = ws + off_pdf;
    float*  ws_sums = ws + off_sums;
    float*  ws_part = ws + off_part;

    const int nib = N / 256;  // 16

    k_stats<<<dim3(6), dim3(256), 0, stream>>>(fused, s1, s2, ws_vn, ws_ab);
    k_pdf<<<dim3(10 * nib * js), dim3(256), 0, stream>>>(ws_vn, ws_ab, ws_part, nib, js);
    k_reduce<<<dim3(10), dim3(256), 0, stream>>>(ws_part, ws_pdf, ws_sums, js);
    k_mi<<<dim3(1), dim3(256), 0, stream>>>(ws_pdf, ws_sums, out);
}